// Round 1
// baseline (127.321 us; speedup 1.0000x reference)
//
#include <hip/hip_runtime.h>

#define HH 4096
#define WW 4096
#define TS 512
#define NBINS 256
#define NT 64
#define PLANE (HH * WW)

// ---------- helpers ----------
__device__ __forceinline__ float wred_min(float v) {
#pragma unroll
    for (int o = 32; o > 0; o >>= 1) v = fminf(v, __shfl_down(v, o, 64));
    return v;
}
__device__ __forceinline__ float wred_max(float v) {
#pragma unroll
    for (int o = 32; o > 0; o >>= 1) v = fmaxf(v, __shfl_down(v, o, 64));
    return v;
}
__device__ __forceinline__ float wred_sum(float v) {
#pragma unroll
    for (int o = 32; o > 0; o >>= 1) v += __shfl_down(v, o, 64);
    return v;
}

// ---------- kernel 0: init scratch (ws is poisoned 0xAA, never re-poisoned) ----------
__global__ __launch_bounds__(256) void k_init(unsigned* __restrict__ hist,
                                              unsigned* __restrict__ minu,
                                              unsigned* __restrict__ maxu) {
    int t = blockIdx.x, tid = threadIdx.x;
    hist[t * NBINS + tid] = 0u;
    if (tid == 0) {
        minu[t] = 0x7F800000u;  // +inf
        maxu[t] = 0u;           // 0.0f (lum >= 0)
    }
}

// ---------- kernel 1: per-tile histogram + min/max ----------
// grid: 64 tiles * 32 row-chunks = 2048 blocks, 256 threads.
// Each block: 16 rows x 512 cols of one tile (8192 px), float4 loads.
#define HIST_LANE(comp)                                              \
    {                                                                \
        float l = (a.comp + b.comp + c.comp) / 3.0f;                 \
        vmin = fminf(vmin, l);                                       \
        vmax = fmaxf(vmax, l);                                       \
        int bb = (int)(l * 256.0f);                                  \
        bb = bb < 0 ? 0 : (bb > 255 ? 255 : bb);                     \
        atomicAdd(&sh[bb], 1u);                                      \
    }

__global__ __launch_bounds__(256) void k_hist(const float* __restrict__ img,
                                              unsigned* __restrict__ ghist,
                                              unsigned* __restrict__ minu,
                                              unsigned* __restrict__ maxu) {
    __shared__ unsigned sh[NBINS];
    __shared__ float smin[4], smax[4];
    int tid = threadIdx.x;
    sh[tid] = 0u;
    __syncthreads();

    int bx = blockIdx.x;
    int t = bx >> 5;        // tile 0..63
    int chunk = bx & 31;    // row chunk 0..31
    int row0 = (t >> 3) * TS + chunk * 16;
    int cb4 = (t & 7) * (TS / 4);  // float4 col base

    const float4* p0 = (const float4*)(img);
    const float4* p1 = (const float4*)(img + PLANE);
    const float4* p2 = (const float4*)(img + 2 * PLANE);

    int colv = tid & 127;
    int rsub = tid >> 7;
    float vmin = 1e30f, vmax = -1e30f;

#pragma unroll
    for (int it = 0; it < 8; ++it) {
        int r = row0 + (it << 1) + rsub;
        size_t idx4 = (size_t)r * (WW / 4) + cb4 + colv;
        float4 a = p0[idx4];
        float4 b = p1[idx4];
        float4 c = p2[idx4];
        HIST_LANE(x)
        HIST_LANE(y)
        HIST_LANE(z)
        HIST_LANE(w)
    }

    // block min/max reduce
    float wmn = wred_min(vmin), wmx = wred_max(vmax);
    if ((tid & 63) == 0) { smin[tid >> 6] = wmn; smax[tid >> 6] = wmx; }
    __syncthreads();
    if (tid == 0) {
        float m = fminf(fminf(smin[0], smin[1]), fminf(smin[2], smin[3]));
        float M = fmaxf(fmaxf(smax[0], smax[1]), fmaxf(smax[2], smax[3]));
        atomicMin(&minu[t], __float_as_uint(m));
        atomicMax(&maxu[t], __float_as_uint(M));
    }
    atomicAdd(&ghist[t * NBINS + tid], sh[tid]);
}

// ---------- kernel 2: clip + cdf per tile ----------
// 64 blocks x 256 threads. Stores alpha-premultiplied normalized cdf + params.
__global__ __launch_bounds__(256) void k_cdf(const unsigned* __restrict__ ghist,
                                             const unsigned* __restrict__ minu,
                                             const unsigned* __restrict__ maxu,
                                             const float* __restrict__ alphas,
                                             float* __restrict__ cdfa,
                                             float* __restrict__ params) {
    __shared__ float sdata[NBINS];
    __shared__ float wsums[4];
    int t = blockIdx.x, tid = threadIdx.x;

    float h = (float)ghist[t * NBINS + tid];
    const float cl = 4096.0f;  // int(4.0 * 512*512 / 256)

    float ex = fmaxf(h - cl, 0.0f);
    float w = wred_sum(ex);
    if ((tid & 63) == 0) wsums[tid >> 6] = w;
    __syncthreads();
    float excess = wsums[0] + wsums[1] + wsums[2] + wsums[3];

    float hc = fminf(h, cl) + excess / 256.0f;

    // inclusive Hillis-Steele scan over 256 bins
    sdata[tid] = hc;
    __syncthreads();
#pragma unroll
    for (int off = 1; off < NBINS; off <<= 1) {
        float v = (tid >= off) ? sdata[tid - off] : 0.0f;
        __syncthreads();
        sdata[tid] += v;
        __syncthreads();
    }
    float cdf = sdata[tid];
    float total = sdata[NBINS - 1];

    float alpha = 0.5f + 0.5f * alphas[t];
    cdfa[t * NBINS + tid] = alpha * (cdf / total);

    if (tid == 0) {
        float tmin = __uint_as_float(minu[t]);
        float tmax = __uint_as_float(maxu[t]);
        bool valid = tmin < tmax;
        params[t * 4 + 0] = tmin;
        params[t * 4 + 1] = valid ? (tmax - tmin) : 1.0f;  // true denominator
        params[t * 4 + 2] = 1.0f - alpha;
        params[t * 4 + 3] = valid ? 1.0f : 0.0f;
    }
}

// ---------- kernel 3: apply ----------
#define APPLY_LANE(comp)                                             \
    {                                                                \
        float l = (a.comp + b.comp + c.comp) / 3.0f;                 \
        float nrm = (l - tp.x) / tp.y;                               \
        int ix = (int)(nrm * 255.0f);                                \
        ix = ix < 0 ? 0 : (ix > 255 ? 255 : ix);                     \
        float enh = ct[ix] + tp.z * l;                               \
        float e0, e1, e2;                                            \
        if (l > 1e-5f) {                                             \
            e0 = enh * (a.comp / l);                                 \
            e1 = enh * (b.comp / l);                                 \
            e2 = enh * (c.comp / l);                                 \
        } else {                                                     \
            e0 = enh; e1 = enh; e2 = enh;                            \
        }                                                            \
        if (tp.w == 0.0f) { e0 = a.comp; e1 = b.comp; e2 = c.comp; } \
        r0.comp = fminf(fmaxf(e0, 0.0f), 1.0f);                      \
        r1.comp = fminf(fmaxf(e1, 0.0f), 1.0f);                      \
        r2.comp = fminf(fmaxf(e2, 0.0f), 1.0f);                      \
    }

__global__ __launch_bounds__(256) void k_apply(const float* __restrict__ img,
                                               float* __restrict__ out,
                                               const float* __restrict__ cdfa,
                                               const float* __restrict__ params) {
    const float4* p0 = (const float4*)(img);
    const float4* p1 = (const float4*)(img + PLANE);
    const float4* p2 = (const float4*)(img + 2 * PLANE);
    float4* o0 = (float4*)(out);
    float4* o1 = (float4*)(out + PLANE);
    float4* o2 = (float4*)(out + 2 * PLANE);

    const int nvec = PLANE / 4;
    int stride = gridDim.x * blockDim.x;
    for (int j = blockIdx.x * blockDim.x + threadIdx.x; j < nvec; j += stride) {
        int p = j << 2;
        int hh = p >> 12;     // row (W = 4096)
        int wq = p & 4095;    // col
        int t = ((hh >> 9) << 3) | (wq >> 9);
        float4 tp = ((const float4*)params)[t];
        const float* ct = cdfa + (t << 8);

        float4 a = p0[j];
        float4 b = p1[j];
        float4 c = p2[j];
        float4 r0, r1, r2;
        APPLY_LANE(x)
        APPLY_LANE(y)
        APPLY_LANE(z)
        APPLY_LANE(w)
        o0[j] = r0;
        o1[j] = r1;
        o2[j] = r2;
    }
}

extern "C" void kernel_launch(void* const* d_in, const int* in_sizes, int n_in,
                              void* d_out, int out_size, void* d_ws, size_t ws_size,
                              hipStream_t stream) {
    const float* img = (const float*)d_in[0];
    const float* alphas = (const float*)d_in[1];
    float* out = (float*)d_out;

    // ws layout (all 4B types; params offset 131584 B is 16B-aligned)
    unsigned* hist = (unsigned*)d_ws;
    unsigned* minu = hist + NT * NBINS;
    unsigned* maxu = minu + NT;
    float* cdfa = (float*)(maxu + NT);
    float* params = cdfa + NT * NBINS;

    k_init<<<NT, NBINS, 0, stream>>>(hist, minu, maxu);
    k_hist<<<2048, 256, 0, stream>>>(img, hist, minu, maxu);
    k_cdf<<<NT, NBINS, 0, stream>>>(hist, minu, maxu, alphas, cdfa, params);
    k_apply<<<2048, 256, 0, stream>>>(img, out, cdfa, params);
}